// Round 13
// baseline (7228.461 us; speedup 1.0000x reference)
//
#include <hip/hip_runtime.h>
#include <cstdint>
#include <cstddef>

typedef unsigned short u16;
typedef unsigned int u32;
typedef float f32x4 __attribute__((ext_vector_type(4)));
typedef _Float16 f16x8 __attribute__((ext_vector_type(8)));
typedef _Float16 f16x2 __attribute__((ext_vector_type(2)));

__device__ __forceinline__ u16 f2h(float x) {
  _Float16 h = (_Float16)x;
  return __builtin_bit_cast(u16, h);
}
__device__ __forceinline__ float sigm(float x) { return 1.f / (1.f + __expf(-x)); }

__device__ __forceinline__ void gll16(const void* g, void* l) {
  __builtin_amdgcn_global_load_lds(
      (const __attribute__((address_space(1))) void*)g,
      (__attribute__((address_space(3))) void*)l, 16, 0, 0);
}

// 8-elem fp16 dot with f32 accumulate: exactly 4 v_dot2_f32_f16.
__device__ __forceinline__ float dot8(f16x8 a, f16x8 b, float acc) {
  union U { f16x8 v; f16x2 h[4]; };
  U ua, ub;
  ua.v = a;
  ub.v = b;
#if __has_builtin(__builtin_amdgcn_fdot2)
#pragma unroll
  for (int i = 0; i < 4; ++i)
    acc = __builtin_amdgcn_fdot2(ua.h[i], ub.h[i], acc, false);
#else
#pragma unroll
  for (int i = 0; i < 8; ++i) acc += (float)a[i] * (float)b[i];
#endif
  return acc;
}

// ============ LSTM-cell GEMM: W in LDS (shared), A direct-to-register ======
// R12 lesson: reg-staged W is read 4x redundantly by the 4 waves sharing wc
// (64KB/step L2) -> regression. Hybrid: W stays LDS-staged (16KB/step, zero
// redundancy); A moves to global->VGPR (2x redundancy = 32KB/step L2; each
// 64B line fully consumed within one load instruction). Per-step pipes:
// LDS ~900cyc (was 1400), L2 ~875cyc, MFMA 620 -> balanced.
struct CellP {
  const u16* A; int lda;   // fp16 activations, row-major
  const u16* W; int ldw;   // fp16 weights row-major [4096][ldw]
  int nt;                  // K/64 this pass (always even)
  const float* bias;       // combined bias, gate-major [4][1024]
  int czero;               // treat c_prev as 0
  u16* d0; int ld0;
  u16* d1; int ld1;
  float* c0;
};

__global__ __launch_bounds__(512, 2) void ck(CellP p) {
  __shared__ __align__(16) char sm[65536];  // 4 x 16KB W-tile buffers
  const int tid = threadIdx.x;
  const int lane = tid & 63, wid = tid >> 6;
  const int wr = wid >> 1, wc = wid & 1;
  // XCD swizzle: each XCD owns 4 whole weight panels (8 row-blocks each)
  const int hw = blockIdx.x;
  const int xcd = hw & 7, idx = hw >> 3;
  const int by = xcd * 4 + (idx >> 3);  // panel [0,32)
  const int bx = idx & 7;               // row block [0,8)
  const int bRow = bx * 128;
  const int nBase = by * 32;
  const int col0 = lane & 15, g4 = lane >> 4;
  const int nt = p.nt;

  f32x4 acc[2][4];
#pragma unroll
  for (int m = 0; m < 2; ++m)
#pragma unroll
    for (int n = 0; n < 4; ++n) acc[m][n] = f32x4{0.f, 0.f, 0.f, 0.f};

  const char* Ab = (const char*)p.A;
  const char* Wb = (const char*)p.W;
  const size_t ldaB = (size_t)p.lda * 2, ldwB = (size_t)p.ldw * 2;

  // W-tile 128x64 -> LDS (linear dest; XOR chunk swizzle on the global
  // source, undone identically on the ds_read side -- R6-proven involution).
  auto stageW = [&](int buf, int kt) {
    char* base = sm + buf * 16384;
    const int kb = kt * 128;
#pragma unroll
    for (int i = 0; i < 2; ++i) {
      const int s = i * 512 + tid;
      const int row = s >> 3, ch = s & 7;
      const int sch = ch ^ (row & 7);
      const int wrow = (row >> 5) * 1024 + nBase + (row & 31);
      gll16(Wb + (size_t)wrow * ldwB + (size_t)(kb + sch * 16),
            base + s * 16);
    }
  };

  // A fragments direct from global. Per lane 4 x 16B; within one
  // instruction lanes cover 16 rows x 64B -> every touched line consumed.
  const char* Abase0 = Ab + (size_t)(bRow + wr * 32 + col0) * ldaB;
  auto loadA = [&](f16x8 (&af)[2][2], int kt) {
    const size_t kb = (size_t)kt * 128;
#pragma unroll
    for (int kf = 0; kf < 2; ++kf)
#pragma unroll
      for (int m = 0; m < 2; ++m)
        af[kf][m] = *(const f16x8*)(Abase0 + (size_t)(m * 16) * ldaB + kb +
                                    (kf * 4 + g4) * 16);
  };

  auto step = [&](int u, const f16x8 (&af)[2][2]) {
    // pending vmem at this point: 4*(loadA u+1 issued) + 2*(stageW u+2 issued)
    const bool w1 = (u + 1 < nt), w2 = (u + 2 < nt);
    if (w1 && w2)  asm volatile("s_waitcnt vmcnt(6)" ::: "memory");
    else if (w1)   asm volatile("s_waitcnt vmcnt(4)" ::: "memory");
    else           asm volatile("s_waitcnt vmcnt(0)" ::: "memory");
    __builtin_amdgcn_s_barrier();
    const char* Wbase = sm + (u & 3) * 16384;
    f16x8 wf[2][4];
#pragma unroll
    for (int kf = 0; kf < 2; ++kf) {
      const int ch = kf * 4 + g4;
#pragma unroll
      for (int n = 0; n < 4; ++n) {
        const int r = n * 32 + wc * 16 + col0;
        wf[kf][n] = *(const f16x8*)(Wbase + r * 128 + ((ch ^ (r & 7)) << 4));
      }
    }
#pragma unroll
    for (int kf = 0; kf < 2; ++kf)
#pragma unroll
      for (int m = 0; m < 2; ++m)
#pragma unroll
        for (int n = 0; n < 4; ++n)
          acc[m][n] = __builtin_amdgcn_mfma_f32_16x16x32_f16(af[kf][m], wf[kf][n],
                                                             acc[m][n], 0, 0, 0);
    // W-buffer reuse distance 4 + one barrier/step: race-free (R6-proven).
  };

  f16x8 afA[2][2], afB[2][2];
  stageW(0, 0);
  stageW(1, 1);
  loadA(afA, 0);
  for (int t = 0; t < nt; t += 2) {  // nt always even
    if (t + 1 < nt) loadA(afB, t + 1);
    if (t + 2 < nt) stageW((t + 2) & 3, t + 2);
    step(t, afA);
    if (t + 1 >= nt) break;
    if (t + 2 < nt) loadA(afA, t + 2);
    if (t + 3 < nt) stageW((t + 3) & 3, t + 3);
    step(t + 1, afB);
  }

  // fused LSTM pointwise epilogue (i/f/g/o in one lane)
  const int j = nBase + wc * 16 + col0;
  const float bi = p.bias[j], bf_ = p.bias[j + 1024];
  const float bg = p.bias[j + 2048], bo = p.bias[j + 3072];
#pragma unroll
  for (int m = 0; m < 2; ++m) {
#pragma unroll
    for (int r = 0; r < 4; ++r) {
      const int b = bRow + wr * 32 + m * 16 + g4 * 4 + r;
      const float gi = acc[m][0][r] + bi;
      const float gf = acc[m][1][r] + bf_;
      const float gg = acc[m][2][r] + bg;
      const float go = acc[m][3][r] + bo;
      const size_t ci = (size_t)b * 1024 + j;
      const float cprev = p.czero ? 0.f : p.c0[ci];
      const float cn = sigm(gf) * cprev + sigm(gi) * tanhf(gg);
      p.c0[ci] = cn;
      const u16 hv = f2h(sigm(go) * tanhf(cn));
      p.d0[(size_t)b * p.ld0 + j] = hv;
      if (p.d1) p.d1[(size_t)b * p.ld1 + j] = hv;
    }
  }
}

// ============ generic 128x128 GEMM (R6-proven), non-cell tasks ============
enum { M_PLAIN = 0, M_TANH = 1, M_FC2 = 3 };

struct GemmP {
  const u16* A; int lda;
  const u16* W; int ldw;   // row-major [N, K]
  int K;
  const float* bias;
  int mode;
  u16* d0; int ld0;
  u16* d1; int ld1;
  float* c0;
  float* c1;
};

__global__ __launch_bounds__(512, 2) void gk(GemmP p) {
  __shared__ __align__(16) char sm[131072];  // 4 x (16K A + 16K W)
  const int tid = threadIdx.x;
  const int lane = tid & 63, wid = tid >> 6;
  const int wr = wid >> 1, wc = wid & 1;
  const int bRow = blockIdx.x * 128;
  const int nBase = blockIdx.y * 128;
  const int col0 = lane & 15, g4 = lane >> 4;

  f32x4 acc[2][4];
#pragma unroll
  for (int m = 0; m < 2; ++m)
#pragma unroll
    for (int n = 0; n < 4; ++n) acc[m][n] = f32x4{0.f, 0.f, 0.f, 0.f};

  const char* Ab = (const char*)p.A;
  const char* Wb = (const char*)p.W;
  const size_t ldaB = (size_t)p.lda * 2, ldwB = (size_t)p.ldw * 2;

  auto stage = [&](int buf, int kt) {
    char* base = sm + buf * 32768;
    const int kb = kt * 128;
#pragma unroll
    for (int i = 0; i < 2; ++i) {
      const int s = i * 512 + tid;
      const int row = s >> 3, ch = s & 7;
      const int sch = ch ^ (row & 7);
      gll16(Ab + (size_t)(bRow + row) * ldaB + (size_t)(kb + sch * 16),
            base + s * 16);
      gll16(Wb + (size_t)(nBase + row) * ldwB + (size_t)(kb + sch * 16),
            base + 16384 + s * 16);
    }
  };

  const int nt = p.K >> 6;
  stage(0, 0);
  stage(1, 1);
  for (int t = 0; t < nt; ++t) {
    if (t + 2 < nt) stage((t + 2) & 3, t + 2);
    const int ahead = (nt - 1 - t < 2) ? (nt - 1 - t) : 2;
    if (ahead == 2)      asm volatile("s_waitcnt vmcnt(8)" ::: "memory");
    else if (ahead == 1) asm volatile("s_waitcnt vmcnt(4)" ::: "memory");
    else                 asm volatile("s_waitcnt vmcnt(0)" ::: "memory");
    __builtin_amdgcn_s_barrier();

    const char* Abase = sm + (t & 3) * 32768;
    const char* Wbase = Abase + 16384;
    f16x8 af[2][2], wf[2][4];
#pragma unroll
    for (int kf = 0; kf < 2; ++kf) {
      const int ch = kf * 4 + g4;
#pragma unroll
      for (int m = 0; m < 2; ++m) {
        const int r = wr * 32 + m * 16 + col0;
        af[kf][m] = *(const f16x8*)(Abase + r * 128 + ((ch ^ (r & 7)) << 4));
      }
#pragma unroll
      for (int n = 0; n < 4; ++n) {
        const int r = wc * 64 + n * 16 + col0;
        wf[kf][n] = *(const f16x8*)(Wbase + r * 128 + ((ch ^ (r & 7)) << 4));
      }
    }
#pragma unroll
    for (int kf = 0; kf < 2; ++kf)
#pragma unroll
      for (int m = 0; m < 2; ++m)
#pragma unroll
        for (int n = 0; n < 4; ++n)
          acc[m][n] = __builtin_amdgcn_mfma_f32_16x16x32_f16(af[kf][m], wf[kf][n],
                                                             acc[m][n], 0, 0, 0);
  }

#pragma unroll
  for (int m = 0; m < 2; ++m)
#pragma unroll
    for (int n = 0; n < 4; ++n)
#pragma unroll
      for (int r = 0; r < 4; ++r) {
        const int b = bRow + wr * 32 + m * 16 + g4 * 4 + r;
        const int j = nBase + wc * 64 + n * 16 + col0;
        float v = acc[m][n][r] + p.bias[j];
        if (p.mode == M_TANH) {
          v = tanhf(v);
          const u16 hv = f2h(v);
          p.d0[(size_t)b * p.ld0 + j] = hv;
          if (p.d1) p.d1[(size_t)b * p.ld1 + j] = hv;
          if (p.c0) p.c0[(size_t)b * 1024 + j] = v;
          if (p.c1) p.c1[(size_t)b * 1024 + j] = v;
        } else if (p.mode == M_PLAIN) {
          p.d0[(size_t)b * p.ld0 + j] = f2h(v);
        } else {  // M_FC2: cols<512 plain -> d0; cols>=512 tanh -> d1
          if (j < 512) p.d0[(size_t)b * p.ld0 + j] = f2h(v);
          else         p.d1[(size_t)b * p.ld1 + (j - 512)] = f2h(tanhf(v));
        }
      }
}

// out projection: 128 blocks x 8 rows; wave owns 2 rows, lane a col pair.
__global__ __launch_bounds__(256, 4) void outk(const u16* A, const u16* W,
                                               const float* bias, u16* pdst,
                                               float* fout) {
  __shared__ __align__(16) u16 As[8][1024];
  const int tid = threadIdx.x;
  const int r0 = blockIdx.x * 8;
  const char* Ab = (const char*)A;
#pragma unroll
  for (int i = 0; i < 4; ++i) {
    const int s = i * 256 + tid;
    const int row = s >> 7, ch = s & 127;
    gll16(Ab + (size_t)(r0 + row) * 4096 + ch * 16, (char*)As + s * 16);
  }
  asm volatile("s_waitcnt vmcnt(0)" ::: "memory");
  __builtin_amdgcn_s_barrier();

  const int wid = tid >> 6, lane = tid & 63;
  const int c0 = lane * 2;
  if (c0 >= 90) return;
  const int row0 = wid * 2;
  const f16x8* a0 = (const f16x8*)As[row0];
  const f16x8* a1 = (const f16x8*)As[row0 + 1];
  const f16x8* w0 = (const f16x8*)(W + (size_t)c0 * 1024);
  const f16x8* w1 = (const f16x8*)(W + (size_t)(c0 + 1) * 1024);
  float acc00 = 0.f, acc01 = 0.f, acc10 = 0.f, acc11 = 0.f;
#pragma unroll 8
  for (int k = 0; k < 128; ++k) {
    const f16x8 wa = w0[k], wb = w1[k];
    const f16x8 aa = a0[k], ab = a1[k];
    acc00 = dot8(aa, wa, acc00);
    acc01 = dot8(aa, wb, acc01);
    acc10 = dot8(ab, wa, acc10);
    acc11 = dot8(ab, wb, acc11);
  }
  const float b0v = bias[c0], b1v = bias[c0 + 1];
  const int b0 = r0 + row0, b1 = b0 + 1;
  float v;
  v = acc00 + b0v;
  pdst[(size_t)b0 * 1664 + c0] = f2h(v);
  fout[(size_t)b0 * 5760 + c0] = sigm(v);
  v = acc01 + b1v;
  pdst[(size_t)b0 * 1664 + c0 + 1] = f2h(v);
  fout[(size_t)b0 * 5760 + c0 + 1] = sigm(v);
  v = acc10 + b0v;
  pdst[(size_t)b1 * 1664 + c0] = f2h(v);
  fout[(size_t)b1 * 5760 + c0] = sigm(v);
  v = acc11 + b1v;
  pdst[(size_t)b1 * 1664 + c0 + 1] = f2h(v);
  fout[(size_t)b1 * 5760 + c0 + 1] = sigm(v);
}

// ---- prologue kernels ----

// row-major fp16 pack: dst[r,0:Ka]=a; [Ka:Ka+gap]=0; then b; pad rows -> 0
__global__ void pack_w(u16* dst, const float* a, int Ka, const float* b, int Kb,
                       int gap, int Kp, int srcRows) {
  const int r = blockIdx.y;
  const int c = blockIdx.x * 256 + threadIdx.x;
  if (c >= Kp) return;
  float v = 0.f;
  if (r < srcRows) {
    if (c < Ka) v = a[(size_t)r * Ka + c];
    else if (c >= Ka + gap && c < Ka + gap + Kb) v = b[(size_t)r * Kb + (c - Ka - gap)];
  }
  dst[(size_t)r * Kp + c] = f2h(v);
}

__global__ void pack_fc1T(u16* dst, const float* src) {
  const int idx = blockIdx.x * 256 + threadIdx.x;
  const int n = idx >> 9, j = idx & 511;
  dst[idx] = f2h(src[(size_t)j * 1024 + n]);
}

__global__ __launch_bounds__(256, 4) void bias_fused(float* bfc2, const float* cfc_w,
                                                     const float* fc1_b,
                                                     const float* cfc_b) {
  const int i = blockIdx.x * 4 + (threadIdx.x >> 6);
  const int lane = threadIdx.x & 63;
  const float4* wrow = (const float4*)(cfc_w + (size_t)i * 512);
  const float4* bv = (const float4*)fc1_b;
  float s = 0.f;
#pragma unroll
  for (int q = 0; q < 2; ++q) {
    const float4 a = wrow[lane * 2 + q], b = bv[lane * 2 + q];
    s += a.x * b.x + a.y * b.y + a.z * b.z + a.w * b.w;
  }
#pragma unroll
  for (int off = 32; off; off >>= 1) s += __shfl_xor(s, off);
  if (lane == 0) bfc2[512 + i] = s + cfc_b[i];
}

struct BiasAll {
  float *bz, *bc0, *bc1, *bfc2, *bb0, *bb1, *bout, *bzero;
  const float *fzb, *ci0, *ch0, *ci1, *ch1, *f1b, *bi0, *bh0, *bi1, *bh1, *ob;
};
__global__ void pack_biases(BiasAll q) {
  int i = blockIdx.x * 256 + threadIdx.x;
  if (i < 1024) { q.bz[i] = q.fzb[i]; return; } i -= 1024;
  if (i < 4096) { q.bc0[i] = q.ci0[i] + q.ch0[i]; return; } i -= 4096;
  if (i < 4096) { q.bc1[i] = q.ci1[i] + q.ch1[i]; return; } i -= 4096;
  if (i < 512)  { q.bfc2[i] = q.f1b[i]; return; } i -= 512;
  if (i < 4096) { q.bb0[i] = q.bi0[i] + q.bh0[i]; return; } i -= 4096;
  if (i < 4096) { q.bb1[i] = q.bi1[i] + q.bh1[i]; return; } i -= 4096;
  if (i < 128)  { q.bout[i] = (i < 90) ? q.ob[i] : 0.f; return; } i -= 128;
  if (i < 1024) { q.bzero[i] = 0.f; }
}

__global__ void conv_h(u16* dst, const float* src, long n) {
  for (long i = (long)blockIdx.x * blockDim.x + threadIdx.x; i < n;
       i += (long)gridDim.x * blockDim.x)
    dst[i] = f2h(src[i]);
}

// zero Xc0 cols 0:512 (cond_in0) and Xb0 cols 512:640 (p slot + 38-col pad).
__global__ void zero_init(u32* xc0, u32* xb0) {
  const int i = blockIdx.x * 256 + threadIdx.x;
  if (i < 1024 * 256) {
    xc0[(i >> 8) * 768 + (i & 255)] = 0;
  } else {
    const int k = i - 1024 * 256;
    xb0[(k >> 6) * 832 + 256 + (k & 63)] = 0;
  }
}

extern "C" void kernel_launch(void* const* d_in, const int* in_sizes, int n_in,
                              void* d_out, int out_size, void* d_ws, size_t ws_size,
                              hipStream_t stream) {
  const float* z      = (const float*)d_in[0];
  const float* fc_z_w = (const float*)d_in[2];
  const float* fc_z_b = (const float*)d_in[3];
  const float* cWih0  = (const float*)d_in[4];
  const float* cWhh0  = (const float*)d_in[5];
  const float* cbih0  = (const float*)d_in[6];
  const float* cbhh0  = (const float*)d_in[7];
  const float* cWih1  = (const float*)d_in[8];
  const float* cWhh1  = (const float*)d_in[9];
  const float* cbih1  = (const float*)d_in[10];
  const float* cbhh1  = (const float*)d_in[11];
  const float* fc1_w  = (const float*)d_in[12];
  const float* fc1_b  = (const float*)d_in[13];
  const float* cfc_w  = (const float*)d_in[14];
  const float* cfc_b  = (const float*)d_in[15];
  const float* bWih0  = (const float*)d_in[16];
  const float* bWhh0  = (const float*)d_in[17];
  const float* bbih0  = (const float*)d_in[18];
  const float* bbhh0  = (const float*)d_in[19];
  const float* bWih1  = (const float*)d_in[20];
  const float* bWhh1  = (const float*)d_in[21];
  const float* bbih1  = (const float*)d_in[22];
  const float* bbhh1  = (const float*)d_in[23];
  const float* out_w  = (const float*)d_in[24];
  const float* out_b  = (const float*)d_in[25];
  float* outp = (float*)d_out;

  char* w = (char*)d_ws;
  auto alloc = [&](size_t bytes) {
    char* p = w;
    w += (bytes + 255) & ~(size_t)255;
    return p;
  };
  u16* Wc0   = (u16*)alloc((size_t)4096 * 1536 * 2);
  u16* Wc1   = (u16*)alloc((size_t)4096 * 2048 * 2);
  u16* Wb0   = (u16*)alloc((size_t)4096 * 1664 * 2);
  u16* Wb1   = (u16*)alloc((size_t)4096 * 2048 * 2);
  u16* Wz    = (u16*)alloc((size_t)1024 * 512 * 2);
  u16* Wfc2  = (u16*)alloc((size_t)1024 * 1024 * 2);
  u16* Wcfc  = (u16*)alloc((size_t)512 * 512 * 2);
  u16* fc1T  = (u16*)alloc((size_t)1024 * 512 * 2);
  u16* Wout  = (u16*)alloc((size_t)128 * 1024 * 2);
  u16* zh    = (u16*)alloc((size_t)1024 * 512 * 2);
  u16* Xc0   = (u16*)alloc((size_t)1024 * 1536 * 2);  // [cond_in 512 | h1 1024]
  u16* Xc1   = (u16*)alloc((size_t)1024 * 2048 * 2);  // [h1 | h2]
  u16* Xb0   = (u16*)alloc((size_t)1024 * 1664 * 2);  // [emb|p|pad|bh1]
  u16* Xb1   = (u16*)alloc((size_t)1024 * 2048 * 2);  // [bh1 | bh2]
  float* cc0  = (float*)alloc((size_t)1024 * 1024 * 4);
  float* cc1  = (float*)alloc((size_t)1024 * 1024 * 4);
  float* cbb0 = (float*)alloc((size_t)1024 * 1024 * 4);
  float* cbb1 = (float*)alloc((size_t)1024 * 1024 * 4);
  float* bz   = (float*)alloc(1024 * 4);
  float* bc0  = (float*)alloc(4096 * 4);
  float* bc1  = (float*)alloc(4096 * 4);
  float* bfc2 = (float*)alloc(1024 * 4);
  float* bb0  = (float*)alloc(4096 * 4);
  float* bb1  = (float*)alloc(4096 * 4);
  float* bout = (float*)alloc(128 * 4);
  float* bzero= (float*)alloc(1024 * 4);

  const dim3 blk(256), blk5(512);
  const dim3 gcell(256);

  // --- prologue: pack weights (row-major fp16), biases, fused fc1->cfc ---
  pack_w<<<dim3(6, 4096), blk, 0, stream>>>(Wc0,  cWih0,  512,  cWhh0,   1024, 0,  1536, 4096);
  pack_w<<<dim3(8, 4096), blk, 0, stream>>>(Wc1,  cWih1,  1024, cWhh1,   1024, 0,  2048, 4096);
  pack_w<<<dim3(7, 4096), blk, 0, stream>>>(Wb0,  bWih0,  602,  bWhh0,   1024, 38, 1664, 4096);
  pack_w<<<dim3(8, 4096), blk, 0, stream>>>(Wb1,  bWih1,  1024, bWhh1,   1024, 0,  2048, 4096);
  pack_w<<<dim3(2, 1024), blk, 0, stream>>>(Wz,   fc_z_w, 512,  nullptr, 0,    0,  512,  1024);
  pack_w<<<dim3(4, 512),  blk, 0, stream>>>(Wfc2, fc1_w,  1024, nullptr, 0,    0,  1024, 512);
  pack_w<<<dim3(2, 512),  blk, 0, stream>>>(Wcfc, cfc_w,  512,  nullptr, 0,    0,  512,  512);
  pack_w<<<dim3(4, 128),  blk, 0, stream>>>(Wout, out_w,  1024, nullptr, 0,    0,  1024, 90);
  pack_fc1T<<<dim3(2048), blk, 0, stream>>>(fc1T, fc1_w);
  {
    BiasAll q{bz, bc0, bc1, bfc2, bb0, bb1, bout, bzero,
              fc_z_b, cbih0, cbhh0, cbih1, cbhh1, fc1_b,
              bbih0, bbhh0, bbih1, bbhh1, out_b};
    pack_biases<<<dim3(80), blk, 0, stream>>>(q);
  }
  bias_fused<<<dim3(128), blk, 0, stream>>>(bfc2, cfc_w, fc1_b, cfc_b);
  conv_h<<<dim3(512), blk, 0, stream>>>(zh, z, 1024L * 512);
  zero_init<<<dim3(1280), blk, 0, stream>>>((u32*)Xc0, (u32*)Xb0);
  {  // Wfused = cfc_w @ fc1_w -> Wfc2 rows 512:1024
    GemmP p{Wcfc, 512, fc1T, 512, 512, bzero, M_PLAIN,
            Wfc2 + (size_t)512 * 1024, 1024, nullptr, 0, nullptr, nullptr};
    gk<<<dim3(4, 8), blk5, 0, stream>>>(p);
  }
  {  // s0 = tanh(z @ Wz^T + bz) -> h1, h2 (fp16) and c1, c2 (f32)
    GemmP p{zh, 512, Wz, 512, 512, bz, M_TANH,
            Xc0 + 512, 1536, Xc1 + 1024, 2048, cc0, cc1};
    gk<<<dim3(8, 8), blk5, 0, stream>>>(p);
  }

  for (int t = 0; t < 16; ++t) {
    {  // conductor layer 0 (K=1536, nt=24)
      CellP p{Xc0, 1536, Wc0, 1536, 24, bc0, 0,
              Xc0 + 512, 1536, Xc1, 2048, cc0};
      ck<<<gcell, blk5, 0, stream>>>(p);
    }
    {  // conductor layer 1 (K=2048, nt=32)
      CellP p{Xc1, 2048, Wc1, 2048, 32, bc1, 0,
              Xc1 + 1024, 2048, nullptr, 0, cc1};
      ck<<<gcell, blk5, 0, stream>>>(p);
    }
    {  // fused fc1+cfc: cond_out -> Xc0 cols 0:512, tanh emb -> Xb0 cols 0:512
      GemmP p{Xc1 + 1024, 2048, Wfc2, 1024, 1024, bfc2, M_FC2,
              Xc0, 1536, Xb0, 1664, nullptr, nullptr};
      gk<<<dim3(8, 8), blk5, 0, stream>>>(p);
    }
    for (int s = 0; s < 4; ++s) {
      {  // bottom layer 0; s==0: bh1=0 & c=0 -> nt=10 (K=640), czero
        CellP p{Xb0, 1664, Wb0, 1664, (s == 0) ? 10 : 26, bb0, (s == 0),
                Xb0 + 640, 1664, Xb1, 2048, cbb0};
        ck<<<gcell, blk5, 0, stream>>>(p);
      }
      {  // bottom layer 1; s==0: bh2=0 & c=0 -> nt=16 (K=1024), czero
        CellP p{Xb1, 2048, Wb1, 2048, (s == 0) ? 16 : 32, bb1, (s == 0),
                Xb1 + 1024, 2048, nullptr, 0, cbb1};
        ck<<<gcell, blk5, 0, stream>>>(p);
      }
      // p = bh2 @ out_w^T + b ; p (fp16) -> Xb0 p-slot, sigmoid -> d_out
      outk<<<dim3(128), blk, 0, stream>>>(Xb1 + 1024, Wout, bout, Xb0 + 512,
                                          outp + (size_t)(t * 4 + s) * 90);
    }
  }
}

// Round 14
// 5723.773 us; speedup vs baseline: 1.2629x; 1.2629x over previous
//
#include <hip/hip_runtime.h>
#include <cstdint>
#include <cstddef>

typedef unsigned short u16;
typedef unsigned int u32;
typedef float f32x4 __attribute__((ext_vector_type(4)));
typedef _Float16 f16x8 __attribute__((ext_vector_type(8)));
typedef _Float16 f16x2 __attribute__((ext_vector_type(2)));

__device__ __forceinline__ u16 f2h(float x) {
  _Float16 h = (_Float16)x;
  return __builtin_bit_cast(u16, h);
}
__device__ __forceinline__ float sigm(float x) { return 1.f / (1.f + __expf(-x)); }

__device__ __forceinline__ void gll16(const void* g, void* l) {
  __builtin_amdgcn_global_load_lds(
      (const __attribute__((address_space(1))) void*)g,
      (__attribute__((address_space(3))) void*)l, 16, 0, 0);
}

// 8-elem fp16 dot with f32 accumulate: exactly 4 v_dot2_f32_f16.
__device__ __forceinline__ float dot8(f16x8 a, f16x8 b, float acc) {
  union U { f16x8 v; f16x2 h[4]; };
  U ua, ub;
  ua.v = a;
  ub.v = b;
#if __has_builtin(__builtin_amdgcn_fdot2)
#pragma unroll
  for (int i = 0; i < 4; ++i)
    acc = __builtin_amdgcn_fdot2(ua.h[i], ub.h[i], acc, false);
#else
#pragma unroll
  for (int i = 0; i < 8; ++i) acc += (float)a[i] * (float)b[i];
#endif
  return acc;
}

// ============ LSTM-cell GEMM: both operands LDS-staged, BK=128 ============
// R12/R13 falsified operand-in-register variants (L2 redundancy/scatter).
// R6 dataflow restored; the recoverable term is SYNC overhead (~700cyc/step,
// 2 waits+barriers per 128 K-elems in R6). BK=128: one {vmcnt(0); barrier;
// stage(t+1); compute} per 128 K-elems. The drain is free in steady state:
// stage(t) was issued right after barrier(t-1) and had the whole compute(t-1)
// phase (~2800cyc >> ~1150cyc L2 service) to complete.
// Safety: per-wave vmcnt(0) + barrier proves ALL waves' stage(t) landed;
// stage(t+1) after the barrier writes the opposite 64KB buffer; reuse
// distance 2 with one barrier/iter -> race-free.
struct CellP {
  const u16* A; int lda;   // fp16 activations, row-major
  const u16* W; int ldw;   // fp16 weights row-major [4096][ldw]
  int nt;                  // K/128 this pass
  const float* bias;       // combined bias, gate-major [4][1024]
  int czero;               // treat c_prev as 0
  u16* d0; int ld0;
  u16* d1; int ld1;
  float* c0;
};

__global__ __launch_bounds__(512, 2) void ck(CellP p) {
  __shared__ __align__(16) char sm[131072];  // 2 x (32KB A-tile + 32KB W-tile)
  const int tid = threadIdx.x;
  const int lane = tid & 63, wid = tid >> 6;
  const int wr = wid >> 1, wc = wid & 1;
  // XCD swizzle: each XCD owns 4 whole weight panels (8 row-blocks each)
  const int hw = blockIdx.x;
  const int xcd = hw & 7, idx = hw >> 3;
  const int by = xcd * 4 + (idx >> 3);  // panel [0,32)
  const int bx = idx & 7;               // row block [0,8)
  const int bRow = bx * 128;
  const int nBase = by * 32;
  const int col0 = lane & 15, g4 = lane >> 4;
  const int nt = p.nt;

  f32x4 acc[2][4];
#pragma unroll
  for (int m = 0; m < 2; ++m)
#pragma unroll
    for (int n = 0; n < 4; ++n) acc[m][n] = f32x4{0.f, 0.f, 0.f, 0.f};

  const char* Ab = (const char*)p.A;
  const char* Wb = (const char*)p.W;
  const size_t ldaB = (size_t)p.lda * 2, ldwB = (size_t)p.ldw * 2;

  // Stage A 128x128 (32KB) + W 128x128 (32KB). Row = 256B = two 128B halves;
  // within each half the R6-proven XOR-chunk swizzle (applied on the GLOBAL
  // source, undone identically on the ds_read side).
  auto stage = [&](int buf, int kt) {
    char* base = sm + buf * 65536;
    const int kb = kt * 256;  // byte offset along K
#pragma unroll
    for (int i = 0; i < 4; ++i) {
      const int s = i * 512 + tid;           // [0,2048) chunk index
      const int row = s >> 4;                // [0,128)
      const int half = (s >> 3) & 1;
      const int ch = s & 7;
      const int sch = ch ^ (row & 7);
      const int off = kb + half * 128 + sch * 16;
      gll16(Ab + (size_t)(bRow + row) * ldaB + off, base + s * 16);
      const int wrow = (row >> 5) * 1024 + nBase + (row & 31);
      gll16(Wb + (size_t)wrow * ldwB + off, base + 32768 + s * 16);
    }
  };

  auto compute = [&](int u) {
    const char* Abase = sm + (u & 1) * 65536;
    const char* Wbase = Abase + 32768;
#pragma unroll
    for (int kf = 0; kf < 4; ++kf) {         // 4 x K=32 slices
      const int c16 = kf * 4 + g4;           // global chunk index [0,16)
      const int half = c16 >> 3, chg = c16 & 7;
      f16x8 af[2], wf[4];
#pragma unroll
      for (int m = 0; m < 2; ++m) {
        const int r = wr * 32 + m * 16 + col0;
        af[m] = *(const f16x8*)(Abase + r * 256 + half * 128 +
                                ((chg ^ (r & 7)) << 4));
      }
#pragma unroll
      for (int n = 0; n < 4; ++n) {
        const int r = n * 32 + wc * 16 + col0;
        wf[n] = *(const f16x8*)(Wbase + r * 256 + half * 128 +
                                ((chg ^ (r & 7)) << 4));
      }
#pragma unroll
      for (int m = 0; m < 2; ++m)
#pragma unroll
        for (int n = 0; n < 4; ++n)
          acc[m][n] = __builtin_amdgcn_mfma_f32_16x16x32_f16(af[m], wf[n],
                                                             acc[m][n], 0, 0, 0);
    }
  };

  stage(0, 0);
  for (int t = 0; t < nt; ++t) {
    asm volatile("s_waitcnt vmcnt(0)" ::: "memory");  // own stage(t) loads done
    __builtin_amdgcn_s_barrier();                     // => ALL waves' loads done
    if (t + 1 < nt) stage((t + 1) & 1, t + 1);        // opposite buffer
    compute(t);
  }

  // fused LSTM pointwise epilogue (i/f/g/o in one lane)
  const int j = nBase + wc * 16 + col0;
  const float bi = p.bias[j], bf_ = p.bias[j + 1024];
  const float bg = p.bias[j + 2048], bo = p.bias[j + 3072];
#pragma unroll
  for (int m = 0; m < 2; ++m) {
#pragma unroll
    for (int r = 0; r < 4; ++r) {
      const int b = bRow + wr * 32 + m * 16 + g4 * 4 + r;
      const float gi = acc[m][0][r] + bi;
      const float gf = acc[m][1][r] + bf_;
      const float gg = acc[m][2][r] + bg;
      const float go = acc[m][3][r] + bo;
      const size_t ci = (size_t)b * 1024 + j;
      const float cprev = p.czero ? 0.f : p.c0[ci];
      const float cn = sigm(gf) * cprev + sigm(gi) * tanhf(gg);
      p.c0[ci] = cn;
      const u16 hv = f2h(sigm(go) * tanhf(cn));
      p.d0[(size_t)b * p.ld0 + j] = hv;
      if (p.d1) p.d1[(size_t)b * p.ld1 + j] = hv;
    }
  }
}

// ============ generic 128x128 GEMM (R6-proven), non-cell tasks ============
enum { M_PLAIN = 0, M_TANH = 1, M_FC2 = 3 };

struct GemmP {
  const u16* A; int lda;
  const u16* W; int ldw;   // row-major [N, K]
  int K;
  const float* bias;
  int mode;
  u16* d0; int ld0;
  u16* d1; int ld1;
  float* c0;
  float* c1;
};

__global__ __launch_bounds__(512, 2) void gk(GemmP p) {
  __shared__ __align__(16) char sm[131072];  // 4 x (16K A + 16K W)
  const int tid = threadIdx.x;
  const int lane = tid & 63, wid = tid >> 6;
  const int wr = wid >> 1, wc = wid & 1;
  const int bRow = blockIdx.x * 128;
  const int nBase = blockIdx.y * 128;
  const int col0 = lane & 15, g4 = lane >> 4;

  f32x4 acc[2][4];
#pragma unroll
  for (int m = 0; m < 2; ++m)
#pragma unroll
    for (int n = 0; n < 4; ++n) acc[m][n] = f32x4{0.f, 0.f, 0.f, 0.f};

  const char* Ab = (const char*)p.A;
  const char* Wb = (const char*)p.W;
  const size_t ldaB = (size_t)p.lda * 2, ldwB = (size_t)p.ldw * 2;

  auto stage = [&](int buf, int kt) {
    char* base = sm + buf * 32768;
    const int kb = kt * 128;
#pragma unroll
    for (int i = 0; i < 2; ++i) {
      const int s = i * 512 + tid;
      const int row = s >> 3, ch = s & 7;
      const int sch = ch ^ (row & 7);
      gll16(Ab + (size_t)(bRow + row) * ldaB + (size_t)(kb + sch * 16),
            base + s * 16);
      gll16(Wb + (size_t)(nBase + row) * ldwB + (size_t)(kb + sch * 16),
            base + 16384 + s * 16);
    }
  };

  const int nt = p.K >> 6;
  stage(0, 0);
  stage(1, 1);
  for (int t = 0; t < nt; ++t) {
    if (t + 2 < nt) stage((t + 2) & 3, t + 2);
    const int ahead = (nt - 1 - t < 2) ? (nt - 1 - t) : 2;
    if (ahead == 2)      asm volatile("s_waitcnt vmcnt(8)" ::: "memory");
    else if (ahead == 1) asm volatile("s_waitcnt vmcnt(4)" ::: "memory");
    else                 asm volatile("s_waitcnt vmcnt(0)" ::: "memory");
    __builtin_amdgcn_s_barrier();

    const char* Abase = sm + (t & 3) * 32768;
    const char* Wbase = Abase + 16384;
    f16x8 af[2][2], wf[2][4];
#pragma unroll
    for (int kf = 0; kf < 2; ++kf) {
      const int ch = kf * 4 + g4;
#pragma unroll
      for (int m = 0; m < 2; ++m) {
        const int r = wr * 32 + m * 16 + col0;
        af[kf][m] = *(const f16x8*)(Abase + r * 128 + ((ch ^ (r & 7)) << 4));
      }
#pragma unroll
      for (int n = 0; n < 4; ++n) {
        const int r = wc * 64 + n * 16 + col0;
        wf[kf][n] = *(const f16x8*)(Wbase + r * 128 + ((ch ^ (r & 7)) << 4));
      }
    }
#pragma unroll
    for (int kf = 0; kf < 2; ++kf)
#pragma unroll
      for (int m = 0; m < 2; ++m)
#pragma unroll
        for (int n = 0; n < 4; ++n)
          acc[m][n] = __builtin_amdgcn_mfma_f32_16x16x32_f16(af[kf][m], wf[kf][n],
                                                             acc[m][n], 0, 0, 0);
  }

#pragma unroll
  for (int m = 0; m < 2; ++m)
#pragma unroll
    for (int n = 0; n < 4; ++n)
#pragma unroll
      for (int r = 0; r < 4; ++r) {
        const int b = bRow + wr * 32 + m * 16 + g4 * 4 + r;
        const int j = nBase + wc * 64 + n * 16 + col0;
        float v = acc[m][n][r] + p.bias[j];
        if (p.mode == M_TANH) {
          v = tanhf(v);
          const u16 hv = f2h(v);
          p.d0[(size_t)b * p.ld0 + j] = hv;
          if (p.d1) p.d1[(size_t)b * p.ld1 + j] = hv;
          if (p.c0) p.c0[(size_t)b * 1024 + j] = v;
          if (p.c1) p.c1[(size_t)b * 1024 + j] = v;
        } else if (p.mode == M_PLAIN) {
          p.d0[(size_t)b * p.ld0 + j] = f2h(v);
        } else {  // M_FC2: cols<512 plain -> d0; cols>=512 tanh -> d1
          if (j < 512) p.d0[(size_t)b * p.ld0 + j] = f2h(v);
          else         p.d1[(size_t)b * p.ld1 + (j - 512)] = f2h(tanhf(v));
        }
      }
}

// out projection: 128 blocks x 8 rows; wave owns 2 rows, lane a col pair.
__global__ __launch_bounds__(256, 4) void outk(const u16* A, const u16* W,
                                               const float* bias, u16* pdst,
                                               float* fout) {
  __shared__ __align__(16) u16 As[8][1024];
  const int tid = threadIdx.x;
  const int r0 = blockIdx.x * 8;
  const char* Ab = (const char*)A;
#pragma unroll
  for (int i = 0; i < 4; ++i) {
    const int s = i * 256 + tid;
    const int row = s >> 7, ch = s & 127;
    gll16(Ab + (size_t)(r0 + row) * 4096 + ch * 16, (char*)As + s * 16);
  }
  asm volatile("s_waitcnt vmcnt(0)" ::: "memory");
  __builtin_amdgcn_s_barrier();

  const int wid = tid >> 6, lane = tid & 63;
  const int c0 = lane * 2;
  if (c0 >= 90) return;
  const int row0 = wid * 2;
  const f16x8* a0 = (const f16x8*)As[row0];
  const f16x8* a1 = (const f16x8*)As[row0 + 1];
  const f16x8* w0 = (const f16x8*)(W + (size_t)c0 * 1024);
  const f16x8* w1 = (const f16x8*)(W + (size_t)(c0 + 1) * 1024);
  float acc00 = 0.f, acc01 = 0.f, acc10 = 0.f, acc11 = 0.f;
#pragma unroll 8
  for (int k = 0; k < 128; ++k) {
    const f16x8 wa = w0[k], wb = w1[k];
    const f16x8 aa = a0[k], ab = a1[k];
    acc00 = dot8(aa, wa, acc00);
    acc01 = dot8(aa, wb, acc01);
    acc10 = dot8(ab, wa, acc10);
    acc11 = dot8(ab, wb, acc11);
  }
  const float b0v = bias[c0], b1v = bias[c0 + 1];
  const int b0 = r0 + row0, b1 = b0 + 1;
  float v;
  v = acc00 + b0v;
  pdst[(size_t)b0 * 1664 + c0] = f2h(v);
  fout[(size_t)b0 * 5760 + c0] = sigm(v);
  v = acc01 + b1v;
  pdst[(size_t)b0 * 1664 + c0 + 1] = f2h(v);
  fout[(size_t)b0 * 5760 + c0 + 1] = sigm(v);
  v = acc10 + b0v;
  pdst[(size_t)b1 * 1664 + c0] = f2h(v);
  fout[(size_t)b1 * 5760 + c0] = sigm(v);
  v = acc11 + b1v;
  pdst[(size_t)b1 * 1664 + c0 + 1] = f2h(v);
  fout[(size_t)b1 * 5760 + c0 + 1] = sigm(v);
}

// ---- prologue kernels ----

// row-major fp16 pack: dst[r,0:Ka]=a; [Ka:Ka+gap]=0; then b; pad rows -> 0
__global__ void pack_w(u16* dst, const float* a, int Ka, const float* b, int Kb,
                       int gap, int Kp, int srcRows) {
  const int r = blockIdx.y;
  const int c = blockIdx.x * 256 + threadIdx.x;
  if (c >= Kp) return;
  float v = 0.f;
  if (r < srcRows) {
    if (c < Ka) v = a[(size_t)r * Ka + c];
    else if (c >= Ka + gap && c < Ka + gap + Kb) v = b[(size_t)r * Kb + (c - Ka - gap)];
  }
  dst[(size_t)r * Kp + c] = f2h(v);
}

__global__ void pack_fc1T(u16* dst, const float* src) {
  const int idx = blockIdx.x * 256 + threadIdx.x;
  const int n = idx >> 9, j = idx & 511;
  dst[idx] = f2h(src[(size_t)j * 1024 + n]);
}

__global__ __launch_bounds__(256, 4) void bias_fused(float* bfc2, const float* cfc_w,
                                                     const float* fc1_b,
                                                     const float* cfc_b) {
  const int i = blockIdx.x * 4 + (threadIdx.x >> 6);
  const int lane = threadIdx.x & 63;
  const float4* wrow = (const float4*)(cfc_w + (size_t)i * 512);
  const float4* bv = (const float4*)fc1_b;
  float s = 0.f;
#pragma unroll
  for (int q = 0; q < 2; ++q) {
    const float4 a = wrow[lane * 2 + q], b = bv[lane * 2 + q];
    s += a.x * b.x + a.y * b.y + a.z * b.z + a.w * b.w;
  }
#pragma unroll
  for (int off = 32; off; off >>= 1) s += __shfl_xor(s, off);
  if (lane == 0) bfc2[512 + i] = s + cfc_b[i];
}

struct BiasAll {
  float *bz, *bc0, *bc1, *bfc2, *bb0, *bb1, *bout, *bzero;
  const float *fzb, *ci0, *ch0, *ci1, *ch1, *f1b, *bi0, *bh0, *bi1, *bh1, *ob;
};
__global__ void pack_biases(BiasAll q) {
  int i = blockIdx.x * 256 + threadIdx.x;
  if (i < 1024) { q.bz[i] = q.fzb[i]; return; } i -= 1024;
  if (i < 4096) { q.bc0[i] = q.ci0[i] + q.ch0[i]; return; } i -= 4096;
  if (i < 4096) { q.bc1[i] = q.ci1[i] + q.ch1[i]; return; } i -= 4096;
  if (i < 512)  { q.bfc2[i] = q.f1b[i]; return; } i -= 512;
  if (i < 4096) { q.bb0[i] = q.bi0[i] + q.bh0[i]; return; } i -= 4096;
  if (i < 4096) { q.bb1[i] = q.bi1[i] + q.bh1[i]; return; } i -= 4096;
  if (i < 128)  { q.bout[i] = (i < 90) ? q.ob[i] : 0.f; return; } i -= 128;
  if (i < 1024) { q.bzero[i] = 0.f; }
}

__global__ void conv_h(u16* dst, const float* src, long n) {
  for (long i = (long)blockIdx.x * blockDim.x + threadIdx.x; i < n;
       i += (long)gridDim.x * blockDim.x)
    dst[i] = f2h(src[i]);
}

// zero Xc0 cols 0:512 (cond_in0) and Xb0 cols 512:640 (p slot + 38-col pad).
__global__ void zero_init(u32* xc0, u32* xb0) {
  const int i = blockIdx.x * 256 + threadIdx.x;
  if (i < 1024 * 256) {
    xc0[(i >> 8) * 768 + (i & 255)] = 0;
  } else {
    const int k = i - 1024 * 256;
    xb0[(k >> 6) * 832 + 256 + (k & 63)] = 0;
  }
}

extern "C" void kernel_launch(void* const* d_in, const int* in_sizes, int n_in,
                              void* d_out, int out_size, void* d_ws, size_t ws_size,
                              hipStream_t stream) {
  const float* z      = (const float*)d_in[0];
  const float* fc_z_w = (const float*)d_in[2];
  const float* fc_z_b = (const float*)d_in[3];
  const float* cWih0  = (const float*)d_in[4];
  const float* cWhh0  = (const float*)d_in[5];
  const float* cbih0  = (const float*)d_in[6];
  const float* cbhh0  = (const float*)d_in[7];
  const float* cWih1  = (const float*)d_in[8];
  const float* cWhh1  = (const float*)d_in[9];
  const float* cbih1  = (const float*)d_in[10];
  const float* cbhh1  = (const float*)d_in[11];
  const float* fc1_w  = (const float*)d_in[12];
  const float* fc1_b  = (const float*)d_in[13];
  const float* cfc_w  = (const float*)d_in[14];
  const float* cfc_b  = (const float*)d_in[15];
  const float* bWih0  = (const float*)d_in[16];
  const float* bWhh0  = (const float*)d_in[17];
  const float* bbih0  = (const float*)d_in[18];
  const float* bbhh0  = (const float*)d_in[19];
  const float* bWih1  = (const float*)d_in[20];
  const float* bWhh1  = (const float*)d_in[21];
  const float* bbih1  = (const float*)d_in[22];
  const float* bbhh1  = (const float*)d_in[23];
  const float* out_w  = (const float*)d_in[24];
  const float* out_b  = (const float*)d_in[25];
  float* outp = (float*)d_out;

  char* w = (char*)d_ws;
  auto alloc = [&](size_t bytes) {
    char* p = w;
    w += (bytes + 255) & ~(size_t)255;
    return p;
  };
  u16* Wc0   = (u16*)alloc((size_t)4096 * 1536 * 2);
  u16* Wc1   = (u16*)alloc((size_t)4096 * 2048 * 2);
  u16* Wb0   = (u16*)alloc((size_t)4096 * 1664 * 2);
  u16* Wb1   = (u16*)alloc((size_t)4096 * 2048 * 2);
  u16* Wz    = (u16*)alloc((size_t)1024 * 512 * 2);
  u16* Wfc2  = (u16*)alloc((size_t)1024 * 1024 * 2);
  u16* Wcfc  = (u16*)alloc((size_t)512 * 512 * 2);
  u16* fc1T  = (u16*)alloc((size_t)1024 * 512 * 2);
  u16* Wout  = (u16*)alloc((size_t)128 * 1024 * 2);
  u16* zh    = (u16*)alloc((size_t)1024 * 512 * 2);
  u16* Xc0   = (u16*)alloc((size_t)1024 * 1536 * 2);  // [cond_in 512 | h1 1024]
  u16* Xc1   = (u16*)alloc((size_t)1024 * 2048 * 2);  // [h1 | h2]
  u16* Xb0   = (u16*)alloc((size_t)1024 * 1664 * 2);  // [emb|p|pad|bh1]
  u16* Xb1   = (u16*)alloc((size_t)1024 * 2048 * 2);  // [bh1 | bh2]
  float* cc0  = (float*)alloc((size_t)1024 * 1024 * 4);
  float* cc1  = (float*)alloc((size_t)1024 * 1024 * 4);
  float* cbb0 = (float*)alloc((size_t)1024 * 1024 * 4);
  float* cbb1 = (float*)alloc((size_t)1024 * 1024 * 4);
  float* bz   = (float*)alloc(1024 * 4);
  float* bc0  = (float*)alloc(4096 * 4);
  float* bc1  = (float*)alloc(4096 * 4);
  float* bfc2 = (float*)alloc(1024 * 4);
  float* bb0  = (float*)alloc(4096 * 4);
  float* bb1  = (float*)alloc(4096 * 4);
  float* bout = (float*)alloc(128 * 4);
  float* bzero= (float*)alloc(1024 * 4);

  const dim3 blk(256), blk5(512);
  const dim3 gcell(256);

  // --- prologue: pack weights (row-major fp16), biases, fused fc1->cfc ---
  pack_w<<<dim3(6, 4096), blk, 0, stream>>>(Wc0,  cWih0,  512,  cWhh0,   1024, 0,  1536, 4096);
  pack_w<<<dim3(8, 4096), blk, 0, stream>>>(Wc1,  cWih1,  1024, cWhh1,   1024, 0,  2048, 4096);
  pack_w<<<dim3(7, 4096), blk, 0, stream>>>(Wb0,  bWih0,  602,  bWhh0,   1024, 38, 1664, 4096);
  pack_w<<<dim3(8, 4096), blk, 0, stream>>>(Wb1,  bWih1,  1024, bWhh1,   1024, 0,  2048, 4096);
  pack_w<<<dim3(2, 1024), blk, 0, stream>>>(Wz,   fc_z_w, 512,  nullptr, 0,    0,  512,  1024);
  pack_w<<<dim3(4, 512),  blk, 0, stream>>>(Wfc2, fc1_w,  1024, nullptr, 0,    0,  1024, 512);
  pack_w<<<dim3(2, 512),  blk, 0, stream>>>(Wcfc, cfc_w,  512,  nullptr, 0,    0,  512,  512);
  pack_w<<<dim3(4, 128),  blk, 0, stream>>>(Wout, out_w,  1024, nullptr, 0,    0,  1024, 90);
  pack_fc1T<<<dim3(2048), blk, 0, stream>>>(fc1T, fc1_w);
  {
    BiasAll q{bz, bc0, bc1, bfc2, bb0, bb1, bout, bzero,
              fc_z_b, cbih0, cbhh0, cbih1, cbhh1, fc1_b,
              bbih0, bbhh0, bbih1, bbhh1, out_b};
    pack_biases<<<dim3(80), blk, 0, stream>>>(q);
  }
  bias_fused<<<dim3(128), blk, 0, stream>>>(bfc2, cfc_w, fc1_b, cfc_b);
  conv_h<<<dim3(512), blk, 0, stream>>>(zh, z, 1024L * 512);
  zero_init<<<dim3(1280), blk, 0, stream>>>((u32*)Xc0, (u32*)Xb0);
  {  // Wfused = cfc_w @ fc1_w -> Wfc2 rows 512:1024
    GemmP p{Wcfc, 512, fc1T, 512, 512, bzero, M_PLAIN,
            Wfc2 + (size_t)512 * 1024, 1024, nullptr, 0, nullptr, nullptr};
    gk<<<dim3(4, 8), blk5, 0, stream>>>(p);
  }
  {  // s0 = tanh(z @ Wz^T + bz) -> h1, h2 (fp16) and c1, c2 (f32)
    GemmP p{zh, 512, Wz, 512, 512, bz, M_TANH,
            Xc0 + 512, 1536, Xc1 + 1024, 2048, cc0, cc1};
    gk<<<dim3(8, 8), blk5, 0, stream>>>(p);
  }

  for (int t = 0; t < 16; ++t) {
    {  // conductor layer 0 (K=1536, nt=12 @ BK=128)
      CellP p{Xc0, 1536, Wc0, 1536, 12, bc0, 0,
              Xc0 + 512, 1536, Xc1, 2048, cc0};
      ck<<<gcell, blk5, 0, stream>>>(p);
    }
    {  // conductor layer 1 (K=2048, nt=16)
      CellP p{Xc1, 2048, Wc1, 2048, 16, bc1, 0,
              Xc1 + 1024, 2048, nullptr, 0, cc1};
      ck<<<gcell, blk5, 0, stream>>>(p);
    }
    {  // fused fc1+cfc: cond_out -> Xc0 cols 0:512, tanh emb -> Xb0 cols 0:512
      GemmP p{Xc1 + 1024, 2048, Wfc2, 1024, 1024, bfc2, M_FC2,
              Xc0, 1536, Xb0, 1664, nullptr, nullptr};
      gk<<<dim3(8, 8), blk5, 0, stream>>>(p);
    }
    for (int s = 0; s < 4; ++s) {
      {  // bottom layer 0; s==0: bh1=0 & c=0 -> nt=5 (K=640), czero
        CellP p{Xb0, 1664, Wb0, 1664, (s == 0) ? 5 : 13, bb0, (s == 0),
                Xb0 + 640, 1664, Xb1, 2048, cbb0};
        ck<<<gcell, blk5, 0, stream>>>(p);
      }
      {  // bottom layer 1; s==0: bh2=0 & c=0 -> nt=8 (K=1024), czero
        CellP p{Xb1, 2048, Wb1, 2048, (s == 0) ? 8 : 16, bb1, (s == 0),
                Xb1 + 1024, 2048, nullptr, 0, cbb1};
        ck<<<gcell, blk5, 0, stream>>>(p);
      }
      // p = bh2 @ out_w^T + b ; p (fp16) -> Xb0 p-slot, sigmoid -> d_out
      outk<<<dim3(128), blk, 0, stream>>>(Xb1 + 1024, Wout, bout, Xb0 + 512,
                                          outp + (size_t)(t * 4 + s) * 90);
    }
  }
}